// Round 2
// baseline (406.030 us; speedup 1.0000x reference)
//
#include <hip/hip_runtime.h>
#include <hip/hip_bf16.h>

// Problem constants: B=16, N=4096 -> NTOK=65536, DIM=1024, T=8, E=64
#define NTOK  65536
#define DIM_  1024
#define NHEAD 8
#define EOUT  64
#define KBLK  32          // DIM_/32 k-steps of the 16x16x32 MFMA
#define CNT_STRIDE 32     // pad each head counter to its own 128B line

// GEMM chunking: chunk = 4 k-blocks = 512B per row, 32 rows -> 16KB
#define CH_ROWB   512
#define CH_LDS    (32 * CH_ROWB)     // 16384
#define NCHUNK    8                  // 8 chunks x 512B = 4KB row (DIM_ f32)
#define NBUF      3                  // 48KB LDS -> 3 blocks/CU

typedef __bf16 bf16x8 __attribute__((ext_vector_type(8)));
typedef float  f32x4  __attribute__((ext_vector_type(4)));
typedef unsigned short u16x8 __attribute__((ext_vector_type(8)));

__device__ inline __bf16 cvt_bf16(float f) {
    __hip_bfloat16 h = __float2bfloat16(f);
    return __builtin_bit_cast(__bf16, h);
}

// Async global->LDS, 16B per lane. LDS dest = wave-uniform base + lane*16.
__device__ inline void gload_lds16(const void* g, void* lds) {
    __builtin_amdgcn_global_load_lds(
        (const __attribute__((address_space(1))) unsigned int*)g,
        (__attribute__((address_space(3))) unsigned int*)lds,
        16, 0, 0);
}

// ---------------------------------------------------------------------------
// Kernel 0 (unchanged, verified): pack W fp32 -> bf16 MFMA B-fragment order,
// AND bucket tokens by head (blocks 0..63; one atomic per head per wave).
// Wp flat index: (((t*KBLK + kb)*4 + et)*64 + lane)*8 + j
//   holds W[t][kb*32 + (lane>>4)*8 + j][et*16 + (lane&15)]
// ---------------------------------------------------------------------------
__global__ __launch_bounds__(256) void pack_and_bucket(
    const float* __restrict__ W, const int* __restrict__ idx,
    unsigned short* __restrict__ Wp, int* __restrict__ cnt,
    int* __restrict__ list)
{
    int x = blockIdx.x * blockDim.x + threadIdx.x;
    {
        int j  = x & 7;
        int l  = (x >> 3) & 63;
        int et = (x >> 9) & 3;
        int kb = (x >> 11) & 31;
        int t  = x >> 16;
        int k = kb * 32 + (l >> 4) * 8 + j;
        int e = et * 16 + (l & 15);
        float v = W[((size_t)t * DIM_ + k) * EOUT + e];
        __hip_bfloat16 h = __float2bfloat16(v);
        Wp[x] = __builtin_bit_cast(unsigned short, h);
    }

    if (blockIdx.x < NTOK / 1024) {
        int wave = threadIdx.x >> 6;
        int lane = threadIdx.x & 63;
        int gw   = blockIdx.x * 4 + wave;        // 256 waves total
        int tbase = gw * 256;
        int t[4];
        #pragma unroll
        for (int c = 0; c < 4; ++c) t[c] = idx[tbase + c * 64 + lane];

        #pragma unroll
        for (int h = 0; h < NHEAD; ++h) {
            unsigned long long m[4];
            int nh = 0;
            #pragma unroll
            for (int c = 0; c < 4; ++c) {
                m[c] = __ballot(t[c] == h);
                nh += __popcll(m[c]);
            }
            int base = 0;
            if (lane == 0 && nh) base = atomicAdd(&cnt[h * CNT_STRIDE], nh);
            base = __shfl(base, 0, 64);
            int pre = 0;
            #pragma unroll
            for (int c = 0; c < 4; ++c) {
                if (t[c] == h) {
                    int rank = __popcll(m[c] & ((1ull << lane) - 1ull));
                    list[h * NTOK + base + pre + rank] = tbase + c * 64 + lane;
                }
                pre += __popcll(m[c]);
            }
        }
    }
}

// ---------------------------------------------------------------------------
// Kernel 1: gathered GEMM.  One block (4 waves) per 32-token tile.
//   Chunk = 512B per row (4 k-blocks) -> 512B DRAM bursts per gathered row
//   (vs 256B before: fewer page activations, better HBM efficiency), 16KB
//   LDS per chunk, 3 buffers (48KB -> 3 blocks/CU), stage-ahead 2, counted
//   vmcnt (8/4/0), raw s_barrier.  Waves split output: wave(rg,ep) computes
//   row-group rg (16 rows) x E-half ep (2 et fragments).
//   LDS staging is lane-linear (global_load_lds constraint); bank conflicts
//   on the strided f32x4 reads are killed by the XOR involution applied to
//   BOTH the global source column and the LDS read column (u ^ (row&15)):
//   16 lanes/row-group land 2 per 4-bank slot = free (m136).
//   B fragments (L2-resident packed Wp) are plain loads inside the unrolled
//   chunk body; compiler schedules them early, 12 waves/CU hide L2 latency.
// Per-wave vm ops per chunk: 4x global_load_lds (+8 B loads, drained by
// compiler waits before each MFMA, hence not in our counted vmcnt).
// ---------------------------------------------------------------------------
__global__ __launch_bounds__(256, 3) void readout_gemm(
    const float* __restrict__ emb, const float* __restrict__ bias,
    const int* __restrict__ cnt, const int* __restrict__ list,
    const unsigned short* __restrict__ Wp, float* __restrict__ out)
{
    __shared__ __align__(16) char smem[NBUF * CH_LDS];   // 48KB

    // Map block -> (head, tile) via prefix of per-head tile counts
    int g = blockIdx.x;
    int head = -1, tile = 0, count = 0, total = 0;
    #pragma unroll
    for (int h = 0; h < NHEAD; ++h) {
        int c = cnt[h * CNT_STRIDE];
        int th = (c + 31) >> 5;
        if (head < 0 && g < total + th) { head = h; tile = g - total; count = c; }
        total += th;
    }
    if (head < 0) return;   // uniform across block

    int wave = threadIdx.x >> 6;
    int lane = threadIdx.x & 63;
    int quad = lane >> 4, l16 = lane & 15;
    int rg = wave >> 1;       // row-group 0/1 (16 rows each)
    int ep = wave & 1;        // E-half: ets {ep*2, ep*2+1}
    int eb = ep * 2;

    const int* mylist = list + head * NTOK;
    int mbase = tile * 32;

    // ---- staging sources: wave stages rows wave*8 .. wave*8+7 ----
    // op i covers rows wave*8+i*2+(lane>>5); lane's 16B unit u = lane&31;
    // global column unit = u ^ (row & 15)  (involution, matches read side)
    const char* gsrc[4];
    int u31 = lane & 31;
    #pragma unroll
    for (int i = 0; i < 4; ++i) {
        int row = wave * 8 + i * 2 + (lane >> 5);
        int m = mbase + row; if (m > count - 1) m = count - 1;
        gsrc[i] = (const char*)(emb + (size_t)mylist[m] * DIM_)
                  + ((u31 ^ (row & 15)) * 16);
    }
    char* ldsw = smem + (wave * 8) * CH_ROWB;   // + buf*CH_LDS (+ i*1024)

    // ---- A-fragment read row: arow & 15 == l16 (rg*16 keeps low bits) ----
    int arow = rg * 16 + l16;

    // ---- B fragments from L2-resident Wp (head block = 65536 ushorts) ----
    const u16x8* wp = reinterpret_cast<const u16x8*>(Wp + (size_t)head * 65536);

    // ---- prologue: stage chunks 0 and 1 ----
    #pragma unroll
    for (int s = 0; s < 2; ++s) {
        char* d = ldsw + s * CH_LDS;
        #pragma unroll
        for (int i = 0; i < 4; ++i)
            gload_lds16(gsrc[i] + s * CH_ROWB, d + i * 1024);
    }

    f32x4 acc[2] = {};

    // ---- main loop: 8 chunks, fully unrolled (compile-time %3 bufs) ----
    #pragma unroll
    for (int c = 0; c < NCHUNK; ++c) {
        // barrier 1: all waves done reading chunk c-1 -> its buf reusable
        asm volatile("s_waitcnt lgkmcnt(0)" ::: "memory");
        __builtin_amdgcn_s_barrier();
        if (c + 2 < NCHUNK) {
            char* d = ldsw + ((c + 2) % NBUF) * CH_LDS;
            #pragma unroll
            for (int i = 0; i < 4; ++i)
                gload_lds16(gsrc[i] + (c + 2) * CH_ROWB, d + i * 1024);
        }
        // counted wait: drain S(c), keep S(c+1),S(c+2) in flight
        if (c < NCHUNK - 2)       asm volatile("s_waitcnt vmcnt(8)" ::: "memory");
        else if (c == NCHUNK - 2) asm volatile("s_waitcnt vmcnt(4)" ::: "memory");
        else                      asm volatile("s_waitcnt vmcnt(0)" ::: "memory");
        __builtin_amdgcn_s_barrier();   // chunk c visible to all waves

        // consume chunk c: 4 k-blocks x (2 ds_read_b128 + cvt + 2 MFMA)
        const char* bb = smem + (c % NBUF) * CH_LDS + arow * CH_ROWB;
        #pragma unroll
        for (int kb = 0; kb < 4; ++kb) {
            int u0 = kb * 8 + quad * 2;
            f32x4 lo = *(const f32x4*)(bb + (((u0 + 0) ^ l16) * 16));
            f32x4 hi = *(const f32x4*)(bb + (((u0 + 1) ^ l16) * 16));
            u16x8 b0 = wp[((c * 4 + kb) * 4 + eb + 0) * 64 + lane];
            u16x8 b1 = wp[((c * 4 + kb) * 4 + eb + 1) * 64 + lane];
            bf16x8 a;
            #pragma unroll
            for (int j = 0; j < 4; ++j) {
                a[j]     = cvt_bf16(lo[j]);
                a[j + 4] = cvt_bf16(hi[j]);
            }
            acc[0] = __builtin_amdgcn_mfma_f32_16x16x32_bf16(
                a, __builtin_bit_cast(bf16x8, b0), acc[0], 0, 0, 0);
            acc[1] = __builtin_amdgcn_mfma_f32_16x16x32_bf16(
                a, __builtin_bit_cast(bf16x8, b1), acc[1], 0, 0, 0);
        }
    }

    // ---- epilogue: C layout col=lane&15, row=(lane>>4)*4+i. Scatter+bias.
    int tok[4];
    #pragma unroll
    for (int i = 0; i < 4; ++i) {
        int m = mbase + rg * 16 + quad * 4 + i;
        tok[i] = (m < count) ? mylist[m] : -1;
    }
    #pragma unroll
    for (int e = 0; e < 2; ++e) {
        float bv = bias[head * EOUT + (eb + e) * 16 + l16];
        #pragma unroll
        for (int i = 0; i < 4; ++i)
            if (tok[i] >= 0)
                __builtin_nontemporal_store(acc[e][i] + bv,
                    &out[(size_t)tok[i] * EOUT + (eb + e) * 16 + l16]);
    }
}

// ---------------------------------------------------------------------------
// ws layout: [0,1024)                  cnt (8 ints @ 128B stride, zeroed/call)
//            [1024, 1024+2MB)          per-head token lists
//            [1024+2MB, 1024+2MB+1MB)  packed bf16 W fragments
// ---------------------------------------------------------------------------
extern "C" void kernel_launch(void* const* d_in, const int* in_sizes, int n_in,
                              void* d_out, int out_size, void* d_ws, size_t ws_size,
                              hipStream_t stream) {
    const float* emb  = (const float*)d_in[0];
    const int*   idx  = (const int*)d_in[1];
    const float* W    = (const float*)d_in[2];
    const float* bias = (const float*)d_in[3];
    float* out = (float*)d_out;

    char* ws = (char*)d_ws;
    int* cnt  = (int*)ws;
    int* list = (int*)(ws + 1024);
    unsigned short* Wp = (unsigned short*)(ws + 1024 + (size_t)NHEAD * NTOK * sizeof(int));

    (void)hipMemsetAsync(cnt, 0, NHEAD * CNT_STRIDE * sizeof(int), stream);
    pack_and_bucket<<<(NHEAD * KBLK * 4 * 64 * 8) / 256, 256, 0, stream>>>(W, idx, Wp, cnt, list);
    // one block per tile; max tiles = sum_h ceil(cnt[h]/32) <= 2048 + 7 = 2055
    readout_gemm<<<2055, 256, 0, stream>>>(emb, bias, cnt, list, Wp, out);
}

// Round 3
// 398.153 us; speedup vs baseline: 1.0198x; 1.0198x over previous
//
#include <hip/hip_runtime.h>
#include <hip/hip_bf16.h>

// Problem constants: B=16, N=4096 -> NTOK=65536, DIM=1024, T=8, E=64
#define NTOK  65536
#define DIM_  1024
#define NHEAD 8
#define EOUT  64
#define KBLK  32          // DIM_/32 k-steps of the 16x16x32 MFMA
#define CNT_STRIDE 32     // pad each head counter to its own 128B line

// GEMM chunking: chunk = 1KB per row (8 k-blocks), 32 rows -> 32KB
#define CH_ROWB   1024
#define CH_LDS    (32 * CH_ROWB)     // 32768
#define NCHUNK    4                  // 4 chunks x 1KB = 4KB row (DIM_ f32)
#define NBUF      2                  // 64KB LDS -> 2 blocks/CU

typedef __bf16 bf16x8 __attribute__((ext_vector_type(8)));
typedef float  f32x4  __attribute__((ext_vector_type(4)));
typedef unsigned short u16x8 __attribute__((ext_vector_type(8)));

__device__ inline __bf16 cvt_bf16(float f) {
    __hip_bfloat16 h = __float2bfloat16(f);
    return __builtin_bit_cast(__bf16, h);
}

// Async global->LDS, 16B per lane. LDS dest = wave-uniform base + lane*16.
__device__ inline void gload_lds16(const void* g, void* lds) {
    __builtin_amdgcn_global_load_lds(
        (const __attribute__((address_space(1))) unsigned int*)g,
        (__attribute__((address_space(3))) unsigned int*)lds,
        16, 0, 0);
}

// ---------------------------------------------------------------------------
// Kernel 0: pack W fp32 -> bf16 MFMA B-fragment order (now COALESCED via an
// LDS bounce: old version issued 524288 scattered 4B reads at 256B lane
// stride), AND bucket tokens by head (blocks 0..63 of 256).
// Wp flat index: (((t*KBLK + kb)*4 + et)*64 + l)*8 + j
//   holds W[t][kb*32 + (l>>4)*8 + j][et*16 + (l&15)]
// Block b (256 total) handles (t = b>>5, kb = b&31): W slab of 32 k-rows x
// 64 e = 8KB contiguous; Wp slice = b*2048 ushorts, written as u16x8/thread.
// ---------------------------------------------------------------------------
__global__ __launch_bounds__(256) void pack_and_bucket(
    const float* __restrict__ W, const int* __restrict__ idx,
    unsigned short* __restrict__ Wp, int* __restrict__ cnt,
    int* __restrict__ list)
{
    __shared__ float lw[2048];
    int b   = blockIdx.x;
    int tid = threadIdx.x;

    // coalesced load: 2048 floats = 256 threads x 2 float4
    const f32x4* src = reinterpret_cast<const f32x4*>(W + (size_t)b * 2048);
    f32x4 v0 = src[tid * 2];
    f32x4 v1 = src[tid * 2 + 1];
    *reinterpret_cast<f32x4*>(&lw[tid * 8])     = v0;
    *reinterpret_cast<f32x4*>(&lw[tid * 8 + 4]) = v1;
    __syncthreads();

    {   // pack: thread (et = tid>>6, l = tid&63) emits 8 contiguous u16
        int et = tid >> 6, l = tid & 63;
        u16x8 o;
        #pragma unroll
        for (int j = 0; j < 8; ++j) {
            float v = lw[((l >> 4) * 8 + j) * 64 + et * 16 + (l & 15)];
            __hip_bfloat16 h = __float2bfloat16(v);
            o[j] = __builtin_bit_cast(unsigned short, h);
        }
        *reinterpret_cast<u16x8*>(Wp + (size_t)b * 2048 + tid * 8) = o;
    }

    // ---- bucket slice: blocks 0..63, wave w owns 256 tokens ----
    if (b < NTOK / 1024) {
        int wave = tid >> 6;
        int lane = tid & 63;
        int gw   = b * 4 + wave;                 // 256 waves total
        int tbase = gw * 256;
        int t[4];
        #pragma unroll
        for (int c = 0; c < 4; ++c) t[c] = idx[tbase + c * 64 + lane];

        #pragma unroll
        for (int h = 0; h < NHEAD; ++h) {
            unsigned long long m[4];
            int nh = 0;
            #pragma unroll
            for (int c = 0; c < 4; ++c) {
                m[c] = __ballot(t[c] == h);
                nh += __popcll(m[c]);
            }
            int base = 0;
            if (lane == 0 && nh) base = atomicAdd(&cnt[h * CNT_STRIDE], nh);
            base = __shfl(base, 0, 64);
            int pre = 0;
            #pragma unroll
            for (int c = 0; c < 4; ++c) {
                if (t[c] == h) {
                    int rank = __popcll(m[c] & ((1ull << lane) - 1ull));
                    list[h * NTOK + base + pre + rank] = tbase + c * 64 + lane;
                }
                pre += __popcll(m[c]);
            }
        }
    }
}

// ---------------------------------------------------------------------------
// Kernel 1: gathered GEMM.  One block (4 waves) per 32-token tile.
//   Chunk = 1KB per gathered row (8 k-blocks): 1KB DRAM bursts, 32KB LDS
//   per chunk, 2 buffers (64KB -> 2 blocks/CU, 8KB staged in flight per wave
//   = 64KB/CU during compute).
//   CRITICAL ORDERING (vmcnt retires IN ISSUE ORDER): per iteration the wave
//   issues  [B(c) reg-loads (16)]  then  [stage S(c+1) (8)]  then waits
//   vmcnt(8) -> drains S(c)+B(c), leaves exactly S(c+1) in flight across the
//   whole consume.  (Round-2 bug: B loads issued AFTER the stage forced the
//   compiler's pre-MFMA waits to drain the staged chunk -> stage-ahead-0.)
//   LDS staging is lane-linear (global_load_lds constraint); bank conflicts
//   on the strided f32x4 reads killed by the XOR involution (unit ^ (row&15))
//   applied to BOTH global source column and LDS read column.
// ---------------------------------------------------------------------------
__global__ __launch_bounds__(256, 2) void readout_gemm(
    const float* __restrict__ emb, const float* __restrict__ bias,
    const int* __restrict__ cnt, const int* __restrict__ list,
    const unsigned short* __restrict__ Wp, float* __restrict__ out)
{
    __shared__ __align__(16) char smem[NBUF * CH_LDS];   // 64KB

    // Map block -> (head, tile) via prefix of per-head tile counts
    int g = blockIdx.x;
    int head = -1, tile = 0, count = 0, total = 0;
    #pragma unroll
    for (int h = 0; h < NHEAD; ++h) {
        int c = cnt[h * CNT_STRIDE];
        int th = (c + 31) >> 5;
        if (head < 0 && g < total + th) { head = h; tile = g - total; count = c; }
        total += th;
    }
    if (head < 0) return;   // uniform across block

    int wave = threadIdx.x >> 6;
    int lane = threadIdx.x & 63;
    int quad = lane >> 4, l16 = lane & 15;
    int rg = wave >> 1;       // row-group 0/1 (16 rows each)
    int ep = wave & 1;        // E-half: ets {ep*2, ep*2+1}
    int eb = ep * 2;

    const int* mylist = list + head * NTOK;
    int mbase = tile * 32;

    // ---- staging sources: wave stages rows wave*8 .. wave*8+7 ----
    // op i covers row wave*8+i: 64 lanes x 16B = the full 1KB row-chunk.
    // global column unit = lane ^ (row & 15)  (involution, low 4 bits only)
    const char* gsrc[8];
    #pragma unroll
    for (int i = 0; i < 8; ++i) {
        int row = wave * 8 + i;
        int m = mbase + row; if (m > count - 1) m = count - 1;
        gsrc[i] = (const char*)(emb + (size_t)mylist[m] * DIM_)
                  + ((lane ^ (row & 15)) * 16);
    }
    char* ldsw = smem + (size_t)(wave * 8) * CH_ROWB;   // + buf*CH_LDS + i*CH_ROWB

    // ---- A-fragment read row: arow & 15 == l16 ----
    int arow = rg * 16 + l16;

    // ---- B fragments from L2-resident Wp (head block = 65536 ushorts) ----
    const u16x8* wp = reinterpret_cast<const u16x8*>(Wp + (size_t)head * 65536);

    // ---- prologue: stage chunk 0 into buf 0 ----
    #pragma unroll
    for (int i = 0; i < 8; ++i)
        gload_lds16(gsrc[i], ldsw + i * CH_ROWB);

    f32x4 acc[2] = {};
    u16x8 B[8][2];

    // ---- main loop: 4 chunks, fully unrolled ----
    #pragma unroll
    for (int c = 0; c < NCHUNK; ++c) {
        // all waves done reading buf of chunk c-1 -> reusable
        asm volatile("s_waitcnt lgkmcnt(0)" ::: "memory");
        __builtin_amdgcn_s_barrier();

        // (1) B(c) reg-loads FIRST (16 vm ops, L2 hits)
        #pragma unroll
        for (int kb = 0; kb < 8; ++kb) {
            B[kb][0] = wp[((c * 8 + kb) * 4 + eb + 0) * 64 + lane];
            B[kb][1] = wp[((c * 8 + kb) * 4 + eb + 1) * 64 + lane];
        }
        // (2) THEN stage S(c+1) (8 vm ops, HBM)
        if (c + 1 < NCHUNK) {
            char* d = ldsw + ((c + 1) & 1) * CH_LDS;
            #pragma unroll
            for (int i = 0; i < 8; ++i)
                gload_lds16(gsrc[i] + (c + 1) * CH_ROWB, d + i * CH_ROWB);
        }
        // (3) counted wait: drains S(c)+B(c); leaves S(c+1) (8 ops) in flight
        if (c + 1 < NCHUNK) asm volatile("s_waitcnt vmcnt(8)" ::: "memory");
        else                asm volatile("s_waitcnt vmcnt(0)" ::: "memory");
        __builtin_amdgcn_s_barrier();   // chunk c visible to all waves

        // consume chunk c: 8 k-blocks x (2 ds_read_b128 + cvt + 2 MFMA)
        const char* bb = smem + (c & 1) * CH_LDS + (size_t)arow * CH_ROWB;
        #pragma unroll
        for (int kb = 0; kb < 8; ++kb) {
            int u0 = kb * 8 + quad * 2;
            f32x4 lo = *(const f32x4*)(bb + (((u0 + 0) ^ l16) * 16));
            f32x4 hi = *(const f32x4*)(bb + (((u0 + 1) ^ l16) * 16));
            bf16x8 a;
            #pragma unroll
            for (int j = 0; j < 4; ++j) {
                a[j]     = cvt_bf16(lo[j]);
                a[j + 4] = cvt_bf16(hi[j]);
            }
            acc[0] = __builtin_amdgcn_mfma_f32_16x16x32_bf16(
                a, __builtin_bit_cast(bf16x8, B[kb][0]), acc[0], 0, 0, 0);
            acc[1] = __builtin_amdgcn_mfma_f32_16x16x32_bf16(
                a, __builtin_bit_cast(bf16x8, B[kb][1]), acc[1], 0, 0, 0);
        }
    }

    // ---- epilogue: C layout col=lane&15, row=(lane>>4)*4+i. Scatter+bias.
    int tok[4];
    #pragma unroll
    for (int i = 0; i < 4; ++i) {
        int m = mbase + rg * 16 + quad * 4 + i;
        tok[i] = (m < count) ? mylist[m] : -1;
    }
    #pragma unroll
    for (int e = 0; e < 2; ++e) {
        float bv = bias[head * EOUT + (eb + e) * 16 + l16];
        #pragma unroll
        for (int i = 0; i < 4; ++i)
            if (tok[i] >= 0)
                __builtin_nontemporal_store(acc[e][i] + bv,
                    &out[(size_t)tok[i] * EOUT + (eb + e) * 16 + l16]);
    }
}

// ---------------------------------------------------------------------------
// ws layout: [0,1024)                  cnt (8 ints @ 128B stride, zeroed/call)
//            [1024, 1024+2MB)          per-head token lists
//            [1024+2MB, 1024+2MB+1MB)  packed bf16 W fragments
// ---------------------------------------------------------------------------
extern "C" void kernel_launch(void* const* d_in, const int* in_sizes, int n_in,
                              void* d_out, int out_size, void* d_ws, size_t ws_size,
                              hipStream_t stream) {
    const float* emb  = (const float*)d_in[0];
    const int*   idx  = (const int*)d_in[1];
    const float* W    = (const float*)d_in[2];
    const float* bias = (const float*)d_in[3];
    float* out = (float*)d_out;

    char* ws = (char*)d_ws;
    int* cnt  = (int*)ws;
    int* list = (int*)(ws + 1024);
    unsigned short* Wp = (unsigned short*)(ws + 1024 + (size_t)NHEAD * NTOK * sizeof(int));

    (void)hipMemsetAsync(cnt, 0, NHEAD * CNT_STRIDE * sizeof(int), stream);
    // 256 blocks: pack (t,kb) slabs + bucket slice on blocks 0..63
    pack_and_bucket<<<256, 256, 0, stream>>>(W, idx, Wp, cnt, list);
    // one block per tile; max tiles = sum_h ceil(cnt[h]/32) <= 2048 + 7 = 2055
    readout_gemm<<<2055, 256, 0, stream>>>(emb, bias, cnt, list, Wp, out);
}